// Round 1
// baseline (28.877 us; speedup 1.0000x reference)
//
#include <hip/hip_runtime.h>

// Contrast-depth loss:
//   d = out - label            (elementwise, [B,32,32] fp32)
//   loss = mean over (b, 8 neighbors, 30x30 centers) of
//          (d[b, y+dy, x+dx] - d[b, y, x])^2 , centers y,x in [1,30]
// Memory-bound: 128 MiB input read, ~21 us at 6.3 TB/s.

#define NBLOCKS 2048
#define THREADS 256

__global__ __launch_bounds__(THREADS, 4) void cdl_partial(
    const float* __restrict__ outp,
    const float* __restrict__ labp,
    float* __restrict__ partial,
    int nimg)
{
    // 32 rows, stride 34 floats (even -> float2-aligned; breaks power-of-2 bank stride)
    __shared__ __align__(16) float d[32][34];
    __shared__ float red[THREADS / 64];

    const int t = threadIdx.x;
    float acc = 0.f;

    for (int b = blockIdx.x; b < nimg; b += gridDim.x) {
        // ---- stage d = out - label into LDS (coalesced float4 loads) ----
        const float4 ov = ((const float4*)outp)[b * 256 + t];
        const float4 lv = ((const float4*)labp)[b * 256 + t];
        const int row = t >> 3;          // 8 float4 per 32-wide row
        const int col = (t & 7) << 2;
        float2* dst = (float2*)&d[row][col];
        dst[0] = make_float2(ov.x - lv.x, ov.y - lv.y);
        dst[1] = make_float2(ov.z - lv.z, ov.w - lv.w);
        __syncthreads();

        // ---- 900 centers as 450 adjacent-pairs; thread g handles centers
        //      (y, xp) and (y, xp+1), xp odd, via six aligned float2 LDS reads ----
        #pragma unroll
        for (int k = 0; k < 2; ++k) {
            const int g = t + k * THREADS;
            if (g < 450) {
                const int y  = g / 15 + 1;          // 1..30
                const int xp = (g % 15) * 2 + 1;    // 1,3,...,29  (xp-1 even)
                const float2* r0 = (const float2*)&d[y - 1][xp - 1];
                const float2* r1 = (const float2*)&d[y    ][xp - 1];
                const float2* r2 = (const float2*)&d[y + 1][xp - 1];
                const float2 a0 = r0[0], b0 = r0[1];
                const float2 a1 = r1[0], b1 = r1[1];
                const float2 a2 = r2[0], b2 = r2[1];
                float v;
                // center0 = d[y][xp] = a1.y
                const float c0 = a1.y;
                v = a0.x - c0; acc += v * v;
                v = a0.y - c0; acc += v * v;
                v = b0.x - c0; acc += v * v;
                v = a1.x - c0; acc += v * v;
                v = b1.x - c0; acc += v * v;
                v = a2.x - c0; acc += v * v;
                v = a2.y - c0; acc += v * v;
                v = b2.x - c0; acc += v * v;
                // center1 = d[y][xp+1] = b1.x
                const float c1 = b1.x;
                v = a0.y - c1; acc += v * v;
                v = b0.x - c1; acc += v * v;
                v = b0.y - c1; acc += v * v;
                v = a1.y - c1; acc += v * v;
                v = b1.y - c1; acc += v * v;
                v = a2.y - c1; acc += v * v;
                v = b2.x - c1; acc += v * v;
                v = b2.y - c1; acc += v * v;
            }
        }
        __syncthreads();   // protect LDS before next image's stores
    }

    // ---- block reduction (wave64 shuffle + LDS) ----
    #pragma unroll
    for (int off = 32; off; off >>= 1) acc += __shfl_down(acc, off, 64);
    const int lane = t & 63, wid = t >> 6;
    if (lane == 0) red[wid] = acc;
    __syncthreads();
    if (t == 0) partial[blockIdx.x] = red[0] + red[1] + red[2] + red[3];
}

__global__ __launch_bounds__(THREADS) void cdl_final(
    const float* __restrict__ partial,
    float* __restrict__ out,
    float inv_count)
{
    __shared__ float red[THREADS / 64];
    const int t = threadIdx.x;
    float acc = 0.f;
    #pragma unroll
    for (int i = 0; i < NBLOCKS / THREADS; ++i) acc += partial[t + i * THREADS];
    #pragma unroll
    for (int off = 32; off; off >>= 1) acc += __shfl_down(acc, off, 64);
    if ((t & 63) == 0) red[t >> 6] = acc;
    __syncthreads();
    if (t == 0) out[0] = (red[0] + red[1] + red[2] + red[3]) * inv_count;
}

extern "C" void kernel_launch(void* const* d_in, const int* in_sizes, int n_in,
                              void* d_out, int out_size, void* d_ws, size_t ws_size,
                              hipStream_t stream) {
    const float* outp = (const float*)d_in[0];
    const float* labp = (const float*)d_in[1];
    float* partial = (float*)d_ws;                 // NBLOCKS floats of scratch
    const int nimg = in_sizes[0] / 1024;           // B (H=W=32)
    const float inv_count = 1.0f / ((float)nimg * 8.0f * 900.0f);

    cdl_partial<<<NBLOCKS, THREADS, 0, stream>>>(outp, labp, partial, nimg);
    cdl_final<<<1, THREADS, 0, stream>>>(partial, (float*)d_out, inv_count);
}